// Round 13
// baseline (320.766 us; speedup 1.0000x reference)
//
#include <hip/hip_runtime.h>
#include <hip/hip_cooperative_groups.h>
#include <hip/hip_bf16.h>
#include <math.h>

namespace cg = cooperative_groups;

#define BS   32
#define NV   512
#define D    128
#define DFF  512
#define E    8
#define NH   8
#define DH   16
#define M_TOK (BS*NV)      // 16384
#define EPS  1e-5f

typedef __hip_bfloat16 bf16;
typedef _Float16 f16;
using sh8   = __attribute__((ext_vector_type(8))) short;
using us4   = __attribute__((ext_vector_type(4))) unsigned short;
using h4    = __attribute__((ext_vector_type(4))) _Float16;
using h8    = __attribute__((ext_vector_type(8))) _Float16;
using f32x4 = __attribute__((ext_vector_type(4))) float;
using f32x16 = __attribute__((ext_vector_type(16))) float;

__device__ __forceinline__ float b2f(bf16 v){ return __bfloat162float(v); }
__device__ __forceinline__ bf16  f2b(float v){ return __float2bfloat16(v); }
__device__ __forceinline__ unsigned short f2bu(float v){
    bf16 b = __float2bfloat16(v);
    return __builtin_bit_cast(unsigned short, b);
}

__device__ __forceinline__ void gload_lds16(const void* g, void* l){
    __builtin_amdgcn_global_load_lds(
        (const __attribute__((address_space(1))) unsigned int*)g,
        (__attribute__((address_space(3))) unsigned int*)l, 16, 0, 0);
}

// prep item ranges
#define PR0 4096                    // b1eff
#define PR1 (PR0 + 262144)          // W1b  (vec4)
#define PR2 (PR1 + 131072)          // W2b  (vec4)
#define PR3 (PR2 + 524288)          // xh   (vec4)
#define PR4 (PR3 + 49152)           // WTq transpose
#define PR5 (PR4 + 16384)           // WoT transpose
#define PREP_ITEMS PR5

#define KSTRIDE 24
#define VSTRIDE 520
#define PSTRIDE 68

struct KP {
    const float *x, *cls, *Wq, *Wk, *Wv, *Wo, *Wg, *W1, *b1, *W2, *b2, *g1, *be1, *g2, *be2;
    float *out, *attn, *gate_out;
    f16  *q, *kbuf, *vbuf, *ctx, *xh, *WTq, *WoT;
    bf16 *x1b, *W1b, *W2b;
    float *yacc, *gate, *b1eff;
};

__global__ __launch_bounds__(512, 2) void k_all(KP p)
{
    cg::grid_group grid = cg::this_grid();
    __shared__ __align__(16) char smem[147456];

    const int bid = blockIdx.x;
    const int t   = threadIdx.x;
    const int w   = t >> 6;
    const int lane = t & 63;

    // ================= Phase P: prep (grid-stride) =================
    for (int tid = bid*512 + t; tid < PREP_ITEMS; tid += 256*512){
        if (tid < PR0){
            int e = tid >> 9, f = tid & 511;
            float acc = p.b1[e*DFF + f];
            const float* wrow = p.W1 + ((size_t)e*DFF + f)*(2*D) + D;
            #pragma unroll 8
            for (int c=0;c<D;++c) acc += p.cls[e*D+c] * wrow[c];
            p.b1eff[tid] = acc;
        } else if (tid < PR1){
            int i = (tid - PR0)*4;
            float4 vv = *(const float4*)(p.W1 + i);
            us4 o; o[0]=f2bu(vv.x); o[1]=f2bu(vv.y); o[2]=f2bu(vv.z); o[3]=f2bu(vv.w);
            *(us4*)(p.W1b + i) = o;
        } else if (tid < PR2){
            int i = (tid - PR1)*4;
            float4 vv = *(const float4*)(p.W2 + i);
            us4 o; o[0]=f2bu(vv.x); o[1]=f2bu(vv.y); o[2]=f2bu(vv.z); o[3]=f2bu(vv.w);
            *(us4*)(p.W2b + i) = o;
        } else if (tid < PR3){
            int i = (tid - PR2)*4;
            float4 vv = *(const float4*)(p.x + i);
            h4 o; o[0]=(f16)vv.x; o[1]=(f16)vv.y; o[2]=(f16)vv.z; o[3]=(f16)vv.w;
            *(h4*)(p.xh + i) = o;
        } else if (tid < PR4){
            int idx = tid - PR3;
            int c = idx>>7, kk = idx&127;
            int which = c>>7, col = c&127;
            const float* W = which==0?p.Wq:(which==1?p.Wk:p.Wv);
            p.WTq[idx] = (f16)W[kk*D + col];
        } else {
            int idx = tid - PR4;
            int c = idx>>7, kk = idx&127;
            p.WoT[idx] = (f16)p.Wo[kk*D + c];
        }
    }
    grid.sync();

    // ================= Phase Q: QKV projection (bm = bid, all 384 cols) =================
    {
        char* Xl = smem;             // 16 KB
        char* Wl = smem + 16384;     // 96 KB
        const f16* xsrc = p.xh + (size_t)bid*64*D;
        #pragma unroll
        for (int i=0;i<2;++i){
            int ci = i*512 + t;
            int row = ci>>4, c16 = (ci&15)^(row&7);
            gload_lds16(xsrc + row*D + c16*8, Xl + (size_t)(i*512 + w*64)*16);
        }
        #pragma unroll
        for (int i=0;i<12;++i){
            int ci = i*512 + t;
            int row = ci>>4, c16 = (ci&15)^(row&7);
            gload_lds16(p.WTq + row*D + c16*8, Wl + (size_t)(i*512 + w*64)*16);
        }
        __syncthreads();

        int rblk = w>>1, ch = w&1;
        int rl = lane&15, g = lane>>4;

        h8 afr[4];
        #pragma unroll
        for (int kk=0;kk<4;++kk){
            int row = rblk*16 + rl;
            int bo = (row<<8) + (kk<<6) + (g<<4); bo ^= (row&7)<<4;
            afr[kk] = *(const h8*)(Xl + bo);
        }
        #pragma unroll
        for (int nt=0; nt<12; ++nt){
            f32x4 acc = (f32x4){0.f,0.f,0.f,0.f};
            #pragma unroll
            for (int kk=0;kk<4;++kk){
                int row = ch*192 + nt*16 + rl;
                int bo = (row<<8)+(kk<<6)+(g<<4); bo ^= (row&7)<<4;
                h8 bfr = *(const h8*)(Wl + bo);
                acc = __builtin_amdgcn_mfma_f32_16x16x32_f16(afr[kk], bfr, acc,0,0,0);
            }
            int cidx = ch*192 + nt*16 + rl;
            int which = cidx>>7, hh=(cidx>>4)&7, d = cidx&15;
            f16* dst = which==0?p.q:(which==1?p.kbuf:p.vbuf);
            #pragma unroll
            for (int j=0;j<4;++j){
                int m = bid*64 + rblk*16 + g*4 + j;
                int b = m>>9, n = m&511;
                dst[(((size_t)(b*NH+hh))*NV + n)*DH + d] = (f16)acc[j];
            }
        }
    }
    grid.sync();

    // ================= Phase A: attention (bh = bid, 4 part-iterations) =================
    {
        f16* Kl  = (f16*)smem;                          // 24 KB
        f16* VT  = (f16*)(smem + 24576);                // 16.25 KB
        f16* pbh = (f16*)(smem + 24576 + 16640);        // 8 waves * 1088 f16 = 17 KB

        int bh = bid;
        const f16* kb = p.kbuf + (size_t)bh*NV*DH;
        const f16* vb = p.vbuf + (size_t)bh*NV*DH;

        if (t < 256){
            int r0 = t*2;
            #pragma unroll
            for (int rr=0; rr<2; ++rr){
                const uint4* src = (const uint4*)(kb + (size_t)(r0+rr)*DH);
                *((uint4*)(Kl + (r0+rr)*KSTRIDE))     = src[0];
                *((uint4*)(Kl + (r0+rr)*KSTRIDE + 8)) = src[1];
            }
            const unsigned short* v0s = (const unsigned short*)(vb + (size_t)r0*DH);
            const unsigned short* v1s = v0s + DH;
            #pragma unroll
            for (int d=0; d<DH; ++d){
                unsigned u = (unsigned)v0s[d] | ((unsigned)v1s[d] << 16);
                *((unsigned*)(VT + d*VSTRIDE + r0)) = u;
            }
        }
        __syncthreads();

        int ql = lane & 15, g = lane >> 4;
        int b = bh >> 3, h = bh & 7;

        for (int part=0; part<4; ++part){
            int q0 = part*128 + w*16;

            h4 qf = *(const h4*)(p.q + ((size_t)bh*NV + q0 + ql)*DH + 4*g);
            #pragma unroll
            for (int i=0;i<4;++i) qf[i] = qf[i] * (_Float16)0.36067376f; // 0.25*log2(e)

            f32x4 S[32];
            #pragma unroll
            for (int tt=0; tt<32; ++tt){
                h4 kf = *(const h4*)(Kl + (tt*16 + ql)*KSTRIDE + 4*g);
                S[tt] = __builtin_amdgcn_mfma_f32_16x16x16f16(kf, qf, (f32x4){0.f,0.f,0.f,0.f}, 0,0,0);
            }
            float sum = 0.f;
            #pragma unroll
            for (int tt=0; tt<32; ++tt)
                #pragma unroll
                for (int j=0;j<4;++j){
                    float pv = exp2f(S[tt][j]);
                    S[tt][j] = pv; sum += pv;
                }
            sum += __shfl_xor(sum, 16);
            sum += __shfl_xor(sum, 32);
            float inv = 1.f/sum;
            #pragma unroll
            for (int tt=0; tt<32; ++tt)
                #pragma unroll
                for (int j=0;j<4;++j) S[tt][j] *= inv;

            f32x4 o0 = (f32x4){0.f,0.f,0.f,0.f}, o1 = (f32x4){0.f,0.f,0.f,0.f};
            f16* pw = pbh + w*(16*PSTRIDE);
            float* attnbase = p.attn + ((size_t)bh*NV + q0)*NV;
            int col16 = lane & 15, qg = lane >> 4;
            #pragma unroll
            for (int c=0; c<8; ++c){
                #pragma unroll
                for (int tt2=0; tt2<4; ++tt2){
                    int tt = c*4 + tt2;
                    h4 pf;
                    pf[0]=(f16)S[tt][0]; pf[1]=(f16)S[tt][1];
                    pf[2]=(f16)S[tt][2]; pf[3]=(f16)S[tt][3];
                    h4 vf = *(const h4*)(VT + ql*VSTRIDE + tt*16 + 4*g);
                    if (tt&1) o1 = __builtin_amdgcn_mfma_f32_16x16x16f16(vf, pf, o1, 0,0,0);
                    else      o0 = __builtin_amdgcn_mfma_f32_16x16x16f16(vf, pf, o0, 0,0,0);
                    *(h4*)(pw + ql*PSTRIDE + tt2*16 + 4*g) = pf;
                }
                asm volatile("" ::: "memory");
                #pragma unroll
                for (int rr=0; rr<4; ++rr){
                    int qq = rr*4 + qg;
                    h4 hv = *(const h4*)(pw + qq*PSTRIDE + col16*4);
                    f32x4 vv;
                    vv[0]=(float)hv[0]; vv[1]=(float)hv[1];
                    vv[2]=(float)hv[2]; vv[3]=(float)hv[3];
                    __builtin_nontemporal_store(vv, (f32x4*)(attnbase + (size_t)qq*NV + c*64 + col16*4));
                }
                asm volatile("" ::: "memory");
            }
            f32x4 o = o0 + o1;
            f16* cb = p.ctx + ((size_t)(b*NV) + q0 + ql)*D + h*DH + 4*g;
            h4 oc; oc[0]=(f16)o[0]; oc[1]=(f16)o[1]; oc[2]=(f16)o[2]; oc[3]=(f16)o[3];
            *(h4*)cb = oc;
        }
    }
    grid.sync();

    // ================= Phase W: Wo + residual + LN1 (bm = bid) =================
    {
        char* Cl = smem;
        char* Wl = smem + 16384;
        float (*lnred)[64][2] = (float (*)[64][2])(smem + 49152);

        const f16* csrc = p.ctx + (size_t)bid*64*D;
        #pragma unroll
        for (int i=0;i<2;++i){
            int ci = i*512 + t;
            int row = ci>>4, c16 = (ci&15)^(row&7);
            gload_lds16(csrc + row*D + c16*8, Cl + (size_t)(i*512 + w*64)*16);
        }
        #pragma unroll
        for (int i=0;i<4;++i){
            int ci = i*512 + t;
            int row = ci>>4, c16 = (ci&15)^(row&7);
            gload_lds16(p.WoT + row*D + c16*8, Wl + (size_t)(i*512 + w*64)*16);
        }
        __syncthreads();

        int rblk = w>>1, ch = w&1;
        int rl = lane&15, g = lane>>4;

        h8 afr[4];
        #pragma unroll
        for (int kk=0;kk<4;++kk){
            int row = rblk*16 + rl;
            int bo = (row<<8) + (kk<<6) + (g<<4); bo ^= (row&7)<<4;
            afr[kk] = *(const h8*)(Cl + bo);
        }
        f32x4 acc[4];
        #pragma unroll
        for (int nt=0;nt<4;++nt) acc[nt] = (f32x4){0.f,0.f,0.f,0.f};
        #pragma unroll
        for (int nt=0; nt<4; ++nt){
            #pragma unroll
            for (int kk=0;kk<4;++kk){
                int row = ch*64 + nt*16 + rl;
                int bo = (row<<8)+(kk<<6)+(g<<4); bo ^= (row&7)<<4;
                h8 bfr = *(const h8*)(Wl + bo);
                acc[nt] = __builtin_amdgcn_mfma_f32_16x16x32_f16(afr[kk], bfr, acc[nt],0,0,0);
            }
        }
        float rowv[4][4];
        #pragma unroll
        for (int j=0;j<4;++j){
            int m = bid*64 + rblk*16 + g*4 + j;
            #pragma unroll
            for (int dt=0;dt<4;++dt){
                int d = ch*64 + dt*16 + rl;
                rowv[j][dt] = acc[dt][j] + p.x[(size_t)m*D + d];
            }
        }
        #pragma unroll
        for (int j=0;j<4;++j){
            float s  = rowv[j][0]+rowv[j][1]+rowv[j][2]+rowv[j][3];
            float s2 = rowv[j][0]*rowv[j][0]+rowv[j][1]*rowv[j][1]
                     + rowv[j][2]*rowv[j][2]+rowv[j][3]*rowv[j][3];
            #pragma unroll
            for (int o=1;o<16;o<<=1){ s += __shfl_xor(s,o); s2 += __shfl_xor(s2,o); }
            if (rl==0){
                int row = rblk*16 + g*4 + j;
                lnred[ch][row][0] = s;
                lnred[ch][row][1] = s2;
            }
        }
        __syncthreads();
        #pragma unroll
        for (int j=0;j<4;++j){
            int row = rblk*16 + g*4 + j;
            float S  = lnred[0][row][0] + lnred[1][row][0];
            float S2 = lnred[0][row][1] + lnred[1][row][1];
            float mean = S*(1.f/D);
            float var  = S2*(1.f/D) - mean*mean;
            float rs = rsqrtf(var + EPS);
            int m = bid*64 + row;
            #pragma unroll
            for (int dt=0;dt<4;++dt){
                int d = ch*64 + dt*16 + rl;
                float o1 = (rowv[j][dt]-mean)*rs*p.g1[d] + p.be1[d];
                p.x1b[(size_t)m*D + d] = f2b(o1);
                p.yacc[(size_t)m*D + d] = o1;
            }
        }
    }
    grid.sync();

    // ================= Phase G: gating (2 variates per block) =================
    {
        float* xm0 = (float*)smem;       // [2][128]
        float* tv0 = xm0 + 256;          // [2][128]
        float* se0 = tv0 + 256;          // [2][8]
        int grp = (t>>7)&1;              // upper half duplicates (benign identical writes)
        int tl = t&127;
        int n = bid*2 + grp;
        float s = 0.f;
        #pragma unroll
        for (int b=0;b<BS;++b) s += p.yacc[((size_t)b*NV + n)*D + tl];
        xm0[grp*128+tl] = s * (1.f/BS);
        __syncthreads();
        float a = 0.f;
        for (int c2=0;c2<D;++c2) a += xm0[grp*128+c2] * p.Wg[c2*D + tl];
        tv0[grp*128+tl] = a;
        __syncthreads();
        if (tl < E){
            float acc=0.f;
            for (int c2=0;c2<D;++c2) acc += tv0[grp*128+c2] * p.cls[tl*D + c2];
            se0[grp*8+tl]=acc;
        }
        __syncthreads();
        if (tl==0){
            float mx=se0[grp*8];
            for(int e=1;e<E;++e) mx=fmaxf(mx,se0[grp*8+e]);
            float sm=0.f; float pr[E];
            for(int e=0;e<E;++e){ pr[e]=__expf(se0[grp*8+e]-mx); sm+=pr[e]; }
            float inv=1.f/sm;
            for(int e=0;e<E;++e){
                p.gate[n*E+e]     = pr[e]*inv;
                p.gate_out[n*E+e] = pr[e]*inv;
            }
        }
    }
    grid.sync();

    // ================= Phase M: MoE + residual + LN2 (bm = bid) =================
    {
        char* Hl = smem + 131072;
        float (*lnred)[4][2] = (float (*)[4][2])Hl;

        int mb = w >> 2, nb = w & 3;
        int l31 = lane & 31, h = lane >> 5;

        sh8 afr[8];
        {
            const bf16* Ab = p.x1b + (size_t)(bid*64 + mb*32 + l31)*D;
            #pragma unroll
            for (int s=0;s<8;++s) afr[s] = *(const sh8*)(Ab + s*16 + h*8);
        }

        f32x16 oacc = {};
        f32x16 acc2e = {};

        auto STAGE = [&](int idx, int buf){
            int e = idx >> 2, fc = idx & 3;
            const bf16* w1src = p.W1b + ((size_t)e*DFF + fc*128)*(2*D);
            const bf16* w2src = p.W2b + (size_t)e*D*DFF + fc*128;
            char* Wa = smem + buf*65536;
            char* Wb = Wa + 32768;
            #pragma unroll
            for (int i=0;i<4;++i){
                int ci  = (i*8 + w)*64 + lane;
                int row = ci >> 4;
                int c16 = (ci & 15) ^ (row & 7);
                gload_lds16(w1src + (size_t)row*256 + c16*8, Wa + (size_t)(i*8+w)*1024);
                gload_lds16(w2src + (size_t)row*512 + c16*8, Wb + (size_t)(i*8+w)*1024);
            }
        };

        STAGE(0, 0);
        asm volatile("s_waitcnt vmcnt(0)" ::: "memory");
        __syncthreads();

        for (int idx=0; idx<32; ++idx){
            int buf = idx & 1;
            int e = idx >> 2, fc = idx & 3;
            char* Wa = smem + buf*65536;
            char* Wb = Wa + 32768;

            if (idx < 31) STAGE(idx+1, buf^1);

            f32x16 acc1 = {};
            {
                int row = nb*32 + l31;
                int rbase = (row<<8);
                int swz = (row&7)<<4;
                #pragma unroll
                for (int s=0;s<8;++s){
                    int bo = (rbase + s*32 + h*16) ^ swz;
                    sh8 bfr = *(const sh8*)(Wa + bo);
                    acc1 = __builtin_amdgcn_mfma_f32_32x32x16_bf16(afr[s], bfr, acc1, 0,0,0);
                }
            }
            {
                float bia = p.b1eff[e*DFF + fc*128 + nb*32 + l31];
                #pragma unroll
                for (int r=0;r<16;++r){
                    int rowm = mb*32 + (r&3) + 8*(r>>2) + 4*h;
                    float v = acc1[r] + bia;
                    v = v > 0.f ? v : 0.f;
                    int bo = (rowm<<8) + ((nb*32 + l31)<<1);
                    bo ^= (rowm&7)<<4;
                    *(bf16*)(Hl + bo) = f2b(v);
                }
            }
            __syncthreads();

            {
                int rowh = mb*32 + l31;
                int hbase = (rowh<<8), hswz = (rowh&7)<<4;
                int roww = nb*32 + l31;
                int wbase = (roww<<8), wswz = (roww&7)<<4;
                #pragma unroll
                for (int s=0;s<8;++s){
                    sh8 hfr = *(const sh8*)(Hl + ((hbase + s*32 + h*16) ^ hswz));
                    sh8 wfr = *(const sh8*)(Wb + ((wbase + s*32 + h*16) ^ wswz));
                    acc2e = __builtin_amdgcn_mfma_f32_32x32x16_bf16(hfr, wfr, acc2e, 0,0,0);
                }
            }

            if (fc == 3){
                int d = nb*32 + l31;
                float bia2 = p.b2[e*D + d];
                #pragma unroll
                for (int r=0;r<16;++r){
                    int m = bid*64 + mb*32 + (r&3) + 8*(r>>2) + 4*h;
                    float gv = p.gate[(m & 511)*E + e];
                    oacc[r] += gv*(acc2e[r] + bia2);
                }
                acc2e = (f32x16){};
            }

            asm volatile("s_waitcnt vmcnt(0)" ::: "memory");
            __syncthreads();
        }

        int d = nb*32 + l31;
        float rowv[16];
        #pragma unroll
        for (int r=0;r<16;++r){
            int m = bid*64 + mb*32 + (r&3) + 8*(r>>2) + 4*h;
            rowv[r] = oacc[r] + p.yacc[(size_t)m*D + d];
        }
        #pragma unroll
        for (int r=0;r<16;++r){
            float s = rowv[r], s2 = rowv[r]*rowv[r];
            #pragma unroll
            for (int o=1;o<32;o<<=1){ s += __shfl_xor(s,o); s2 += __shfl_xor(s2,o); }
            if (l31==0){
                int rowl = mb*32 + (r&3) + 8*(r>>2) + 4*h;
                lnred[rowl][nb][0] = s;
                lnred[rowl][nb][1] = s2;
            }
        }
        __syncthreads();
        #pragma unroll
        for (int r=0;r<16;++r){
            int rowl = mb*32 + (r&3) + 8*(r>>2) + 4*h;
            float S  = lnred[rowl][0][0]+lnred[rowl][1][0]+lnred[rowl][2][0]+lnred[rowl][3][0];
            float S2 = lnred[rowl][0][1]+lnred[rowl][1][1]+lnred[rowl][2][1]+lnred[rowl][3][1];
            float mean = S*(1.f/D);
            float var  = S2*(1.f/D) - mean*mean;
            float rs = rsqrtf(var + EPS);
            int m = bid*64 + rowl;
            p.out[(size_t)m*D + d] = (rowv[r]-mean)*rs*p.g2[d] + p.be2[d];
        }
    }
}

extern "C" void kernel_launch(void* const* d_in, const int* in_sizes, int n_in,
                              void* d_out, int out_size, void* d_ws, size_t ws_size,
                              hipStream_t stream)
{
    KP p;
    p.x   = (const float*)d_in[0];
    p.cls = (const float*)d_in[1];
    p.Wq  = (const float*)d_in[2];
    p.Wk  = (const float*)d_in[3];
    p.Wv  = (const float*)d_in[4];
    p.Wo  = (const float*)d_in[5];
    p.Wg  = (const float*)d_in[6];
    p.W1  = (const float*)d_in[7];
    p.b1  = (const float*)d_in[8];
    p.W2  = (const float*)d_in[9];
    p.b2  = (const float*)d_in[10];
    p.g1  = (const float*)d_in[11];
    p.be1 = (const float*)d_in[12];
    p.g2  = (const float*)d_in[13];
    p.be2 = (const float*)d_in[14];

    p.out      = (float*)d_out;
    p.attn     = p.out + (size_t)M_TOK*D;
    p.gate_out = p.attn + (size_t)BS*NH*NV*NV;

    char* ws = (char*)d_ws;
    size_t off = 0;
    auto alloc = [&](size_t bytes)->void*{ void* q = ws + off; off += (bytes + 255) & ~(size_t)255; return q; };
    p.q    = (f16*)  alloc((size_t)M_TOK*D*2);
    p.kbuf = (f16*)  alloc((size_t)M_TOK*D*2);
    p.vbuf = (f16*)  alloc((size_t)M_TOK*D*2);
    p.ctx  = (f16*)  alloc((size_t)M_TOK*D*2);
    p.x1b  = (bf16*) alloc((size_t)M_TOK*D*2);
    p.yacc = (float*)alloc((size_t)M_TOK*D*4);
    p.gate = (float*)alloc((size_t)NV*E*4);
    p.b1eff= (float*)alloc((size_t)E*DFF*4);
    p.W1b  = (bf16*) alloc((size_t)E*DFF*2*D*2);
    p.W2b  = (bf16*) alloc((size_t)E*D*DFF*2);
    p.xh   = (f16*)  alloc((size_t)M_TOK*D*2);
    p.WTq  = (f16*)  alloc((size_t)384*D*2);
    p.WoT  = (f16*)  alloc((size_t)D*D*2);

    void* args[] = { (void*)&p };
    hipLaunchCooperativeKernel((const void*)k_all, dim3(256), dim3(512), args, 0, stream);
}

// Round 14
// 184.201 us; speedup vs baseline: 1.7414x; 1.7414x over previous
//
#include <hip/hip_runtime.h>
#include <hip/hip_bf16.h>
#include <math.h>

#define BS   32
#define NV   512
#define D    128
#define DFF  512
#define E    8
#define NH   8
#define DH   16
#define M_TOK (BS*NV)      // 16384
#define EPS  1e-5f

typedef __hip_bfloat16 bf16;
typedef _Float16 f16;
using sh8   = __attribute__((ext_vector_type(8))) short;    // 8 bf16 (4 VGPRs)
using us4   = __attribute__((ext_vector_type(4))) unsigned short;
using h4    = __attribute__((ext_vector_type(4))) _Float16;
using h8    = __attribute__((ext_vector_type(8))) _Float16; // 8 f16 (4 VGPRs)
using f32x4 = __attribute__((ext_vector_type(4))) float;
using f32x16 = __attribute__((ext_vector_type(16))) float;

__device__ __forceinline__ float b2f(bf16 v){ return __bfloat162float(v); }
__device__ __forceinline__ bf16  f2b(float v){ return __float2bfloat16(v); }
__device__ __forceinline__ unsigned short f2bu(float v){
    bf16 b = __float2bfloat16(v);
    return __builtin_bit_cast(unsigned short, b);
}

// async global->LDS, 16B per lane; LDS dest is wave-uniform base + lane*16
__device__ __forceinline__ void gload_lds16(const void* g, void* l){
    __builtin_amdgcn_global_load_lds(
        (const __attribute__((address_space(1))) unsigned int*)g,
        (__attribute__((address_space(3))) unsigned int*)l, 16, 0, 0);
}

// ---------------- K0: consolidated prep (all conversions + b1eff) ----------------
#define PR0 4096                    // b1eff
#define PR1 (PR0 + 262144)          // W1b  (vec4)
#define PR2 (PR1 + 131072)          // W2b  (vec4)
#define PR3 (PR2 + 524288)          // xh   (vec4)
#define PR4 (PR3 + 49152)           // WTq transpose
#define PR5 (PR4 + 16384)           // WoT transpose
#define PREP_ITEMS PR5              // 987,136
__global__ __launch_bounds__(256) void k_prep(
    const float* __restrict__ W1, const float* __restrict__ W2,
    const float* __restrict__ x,  const float* __restrict__ Wq,
    const float* __restrict__ Wk, const float* __restrict__ Wv,
    const float* __restrict__ Wo, const float* __restrict__ b1,
    const float* __restrict__ cls,
    bf16* __restrict__ W1b, bf16* __restrict__ W2b, f16* __restrict__ xh,
    f16* __restrict__ WTq, f16* __restrict__ WoT, float* __restrict__ b1eff)
{
    int tid = blockIdx.x*256 + threadIdx.x;
    if (tid < PR0){
        int e = tid >> 9, f = tid & 511;
        float acc = b1[e*DFF + f];
        const float* wrow = W1 + ((size_t)e*DFF + f)*(2*D) + D;
        #pragma unroll 8
        for (int c=0;c<D;++c) acc += cls[e*D+c] * wrow[c];
        b1eff[tid] = acc;
    } else if (tid < PR1){
        int i = (tid - PR0)*4;
        float4 vv = *(const float4*)(W1 + i);
        us4 o; o[0]=f2bu(vv.x); o[1]=f2bu(vv.y); o[2]=f2bu(vv.z); o[3]=f2bu(vv.w);
        *(us4*)(W1b + i) = o;
    } else if (tid < PR2){
        int i = (tid - PR1)*4;
        float4 vv = *(const float4*)(W2 + i);
        us4 o; o[0]=f2bu(vv.x); o[1]=f2bu(vv.y); o[2]=f2bu(vv.z); o[3]=f2bu(vv.w);
        *(us4*)(W2b + i) = o;
    } else if (tid < PR3){
        int i = (tid - PR2)*4;
        float4 vv = *(const float4*)(x + i);
        h4 o; o[0]=(f16)vv.x; o[1]=(f16)vv.y; o[2]=(f16)vv.z; o[3]=(f16)vv.w;
        *(h4*)(xh + i) = o;
    } else if (tid < PR4){
        int idx = tid - PR3;
        int c = idx>>7, kk = idx&127;
        int which = c>>7, col = c&127;
        const float* W = which==0?Wq:(which==1?Wk:Wv);
        WTq[idx] = (f16)W[kk*D + col];
    } else if (tid < PR5){
        int idx = tid - PR4;
        int c = idx>>7, kk = idx&127;
        WoT[idx] = (f16)Wo[kk*D + c];
    }
}

// ---------------- K1: QKV projection (MFMA f16 GEMM) ----------------
__global__ __launch_bounds__(512) void k_qkv_mfma(
    const f16* __restrict__ xh, const f16* __restrict__ WT,
    f16* __restrict__ q, f16* __restrict__ k, f16* __restrict__ v)
{
    __shared__ __align__(16) char smem[65536];  // Xl 16K | Wl 48K
    char* Xl = smem;
    char* Wl = smem + 16384;
    int t = threadIdx.x;
    int w = t>>6, lane = t&63;
    int bm = blockIdx.x, nh = blockIdx.y;

    const f16* xsrc = xh + (size_t)bm*64*D;
    #pragma unroll
    for (int i=0;i<2;++i){
        int ci = i*512 + t;
        int row = ci>>4, c16 = (ci&15)^(row&7);
        gload_lds16(xsrc + row*D + c16*8, Xl + (size_t)(i*512 + w*64)*16);
    }
    const f16* wsrc = WT + (size_t)nh*192*D;
    #pragma unroll
    for (int i=0;i<6;++i){
        int ci = i*512 + t;
        int row = ci>>4, c16 = (ci&15)^(row&7);
        gload_lds16(wsrc + row*D + c16*8, Wl + (size_t)(i*512 + w*64)*16);
    }
    __syncthreads();

    int rblk = w>>1, ch = w&1;
    int rl = lane&15, g = lane>>4;

    h8 afr[4];
    #pragma unroll
    for (int kk=0;kk<4;++kk){
        int row = rblk*16 + rl;
        int bo = (row<<8) + (kk<<6) + (g<<4); bo ^= (row&7)<<4;
        afr[kk] = *(const h8*)(Xl + bo);
    }
    f32x4 acc[6];
    #pragma unroll
    for (int nt=0;nt<6;++nt) acc[nt] = (f32x4){0.f,0.f,0.f,0.f};
    #pragma unroll
    for (int nt=0; nt<6; ++nt){
        #pragma unroll
        for (int kk=0;kk<4;++kk){
            int row = ch*96 + nt*16 + rl;
            int bo = (row<<8)+(kk<<6)+(g<<4); bo ^= (row&7)<<4;
            h8 bfr = *(const h8*)(Wl + bo);
            acc[nt] = __builtin_amdgcn_mfma_f32_16x16x32_f16(afr[kk], bfr, acc[nt],0,0,0);
        }
    }
    #pragma unroll
    for (int nt=0;nt<6;++nt){
        int cidx = nh*192 + ch*96 + nt*16 + rl;
        int which = cidx>>7, hh=(cidx>>4)&7, d = cidx&15;
        f16* dst = which==0?q:(which==1?k:v);
        #pragma unroll
        for (int j=0;j<4;++j){
            int m = bm*64 + rblk*16 + g*4 + j;
            int b = m>>9, n = m&511;
            dst[(((size_t)(b*NH+hh))*NV + n)*DH + d] = (f16)acc[nt][j];
        }
    }
}

// ---------------- K2: MFMA attention, occupancy-optimized ----------------
// P kept in f16 registers (64 VGPR instead of 128), P-transpose buffer aliased
// onto Kl (dead after QK^T). LDS 36.25 KB -> 4 blocks/CU; VGPR<=128 -> 16 waves/CU.
#define KSTRIDE 20
#define VSTRIDE 520
#define PSTRIDE 68
__global__ __launch_bounds__(256, 4) void k_attn2(
    const f16* __restrict__ q, const f16* __restrict__ kin, const f16* __restrict__ vin,
    float* __restrict__ attn_out, f16* __restrict__ ctx)
{
    __shared__ f16  Kl[512*KSTRIDE];       // 20 KB; reused as P-transpose after QK^T
    __shared__ f16  VT[16*VSTRIDE];        // 16.25 KB

    int bh = blockIdx.x;
    int t  = threadIdx.x;
    const f16* kb = kin + (size_t)bh*NV*DH;
    const f16* vb = vin + (size_t)bh*NV*DH;

    {
        int r0 = t*2;
        #pragma unroll
        for (int rr=0; rr<2; ++rr){
            const uint2* src = (const uint2*)(kb + (size_t)(r0+rr)*DH);
            uint2* dst = (uint2*)(Kl + (r0+rr)*KSTRIDE);
            dst[0]=src[0]; dst[1]=src[1]; dst[2]=src[2]; dst[3]=src[3];
        }
        const unsigned short* v0s = (const unsigned short*)(vb + (size_t)r0*DH);
        const unsigned short* v1s = v0s + DH;
        #pragma unroll
        for (int d=0; d<DH; ++d){
            unsigned u = (unsigned)v0s[d] | ((unsigned)v1s[d] << 16);
            *((unsigned*)(VT + d*VSTRIDE + r0)) = u;
        }
    }
    __syncthreads();

    int wave = t >> 6, lane = t & 63;
    int ql = lane & 15, g = lane >> 4;
    int q0 = blockIdx.y*64 + wave*16;

    h4 qf = *(const h4*)(q + ((size_t)bh*NV + q0 + ql)*DH + 4*g);
    #pragma unroll
    for (int i=0;i<4;++i) qf[i] = qf[i] * (_Float16)0.36067376f; // 0.25*log2(e)

    // QK^T + exp2 + running sum; P stored unnormalized in f16 regs
    h4 P16[32];
    float sum = 0.f;
    #pragma unroll
    for (int tt=0; tt<32; ++tt){
        h4 kf = *(const h4*)(Kl + (tt*16 + ql)*KSTRIDE + 4*g);
        f32x4 S = __builtin_amdgcn_mfma_f32_16x16x16f16(kf, qf, (f32x4){0.f,0.f,0.f,0.f}, 0,0,0);
        float p0 = exp2f(S[0]), p1 = exp2f(S[1]), p2 = exp2f(S[2]), p3 = exp2f(S[3]);
        sum += (p0+p1) + (p2+p3);
        h4 ph; ph[0]=(f16)p0; ph[1]=(f16)p1; ph[2]=(f16)p2; ph[3]=(f16)p3;
        P16[tt] = ph;
    }
    sum += __shfl_xor(sum, 16);
    sum += __shfl_xor(sum, 32);
    float inv = 1.f/sum;
    f16 hinv = (f16)inv;

    __syncthreads();   // all waves done reading Kl -> safe to overlay P buffer

    f32x4 o0 = (f32x4){0.f,0.f,0.f,0.f}, o1 = (f32x4){0.f,0.f,0.f,0.f};
    f16* pw = ((f16*)Kl) + wave*(16*PSTRIDE);
    float* attnbase = attn_out + ((size_t)bh*NV + q0)*NV;
    int col16 = lane & 15, qg = lane >> 4;
    #pragma unroll
    for (int c=0; c<8; ++c){
        #pragma unroll
        for (int tt2=0; tt2<4; ++tt2){
            int tt = c*4 + tt2;
            h4 pf = P16[tt];
            pf[0] = pf[0]*hinv; pf[1] = pf[1]*hinv;
            pf[2] = pf[2]*hinv; pf[3] = pf[3]*hinv;
            h4 vf = *(const h4*)(VT + ql*VSTRIDE + tt*16 + 4*g);
            if (tt&1) o1 = __builtin_amdgcn_mfma_f32_16x16x16f16(vf, pf, o1, 0,0,0);
            else      o0 = __builtin_amdgcn_mfma_f32_16x16x16f16(vf, pf, o0, 0,0,0);
            *(h4*)(pw + ql*PSTRIDE + tt2*16 + 4*g) = pf;   // one b64 write
        }
        asm volatile("" ::: "memory");   // compiler fence; HW keeps per-wave DS order
        #pragma unroll
        for (int rr=0; rr<4; ++rr){
            int qq = rr*4 + qg;
            h4 hv = *(const h4*)(pw + qq*PSTRIDE + col16*4);   // one b64 read
            f32x4 vv;
            vv[0]=(float)hv[0]; vv[1]=(float)hv[1];
            vv[2]=(float)hv[2]; vv[3]=(float)hv[3];
            // per instruction: 4 rows x (16 lanes x 16B = 256 B contiguous)
            __builtin_nontemporal_store(vv, (f32x4*)(attnbase + (size_t)qq*NV + c*64 + col16*4));
        }
        asm volatile("" ::: "memory");   // fence before next chunk's pw writes (WAR)
    }
    f32x4 o = o0 + o1;
    int b = bh >> 3, h = bh & 7;
    f16* cb = ctx + ((size_t)(b*NV) + q0 + ql)*D + h*DH + 4*g;
    h4 oc; oc[0]=(f16)o[0]; oc[1]=(f16)o[1]; oc[2]=(f16)o[2]; oc[3]=(f16)o[3];
    *(h4*)cb = oc;
}

// ---------------- K3: Wo projection + residual + LN1 (MFMA) ----------------
__global__ __launch_bounds__(512) void k_woln_mfma(
    const f16* __restrict__ ctx, const f16* __restrict__ WoT,
    const float* __restrict__ x, const float* __restrict__ g1, const float* __restrict__ be1,
    bf16* __restrict__ x1b, float* __restrict__ yacc)
{
    __shared__ __align__(16) char smem[49152];  // Cl 16K | Wl 32K
    __shared__ float lnred[2][64][2];
    char* Cl = smem;
    char* Wl = smem + 16384;
    int t = threadIdx.x;
    int w = t>>6, lane = t&63;
    int bm = blockIdx.x;

    const f16* csrc = ctx + (size_t)bm*64*D;
    #pragma unroll
    for (int i=0;i<2;++i){
        int ci = i*512 + t;
        int row = ci>>4, c16 = (ci&15)^(row&7);
        gload_lds16(csrc + row*D + c16*8, Cl + (size_t)(i*512 + w*64)*16);
    }
    #pragma unroll
    for (int i=0;i<4;++i){
        int ci = i*512 + t;
        int row = ci>>4, c16 = (ci&15)^(row&7);
        gload_lds16(WoT + row*D + c16*8, Wl + (size_t)(i*512 + w*64)*16);
    }
    __syncthreads();

    int rblk = w>>1, ch = w&1;
    int rl = lane&15, g = lane>>4;

    h8 afr[4];
    #pragma unroll
    for (int kk=0;kk<4;++kk){
        int row = rblk*16 + rl;
        int bo = (row<<8) + (kk<<6) + (g<<4); bo ^= (row&7)<<4;
        afr[kk] = *(const h8*)(Cl + bo);
    }
    f32x4 acc[4];
    #pragma unroll
    for (int nt=0;nt<4;++nt) acc[nt] = (f32x4){0.f,0.f,0.f,0.f};
    #pragma unroll
    for (int nt=0; nt<4; ++nt){
        #pragma unroll
        for (int kk=0;kk<4;++kk){
            int row = ch*64 + nt*16 + rl;
            int bo = (row<<8)+(kk<<6)+(g<<4); bo ^= (row&7)<<4;
            h8 bfr = *(const h8*)(Wl + bo);
            acc[nt] = __builtin_amdgcn_mfma_f32_16x16x32_f16(afr[kk], bfr, acc[nt],0,0,0);
        }
    }

    float rowv[4][4];
    #pragma unroll
    for (int j=0;j<4;++j){
        int m = bm*64 + rblk*16 + g*4 + j;
        #pragma unroll
        for (int dt=0;dt<4;++dt){
            int d = ch*64 + dt*16 + rl;
            rowv[j][dt] = acc[dt][j] + x[(size_t)m*D + d];
        }
    }
    #pragma unroll
    for (int j=0;j<4;++j){
        float s  = rowv[j][0]+rowv[j][1]+rowv[j][2]+rowv[j][3];
        float s2 = rowv[j][0]*rowv[j][0]+rowv[j][1]*rowv[j][1]
                 + rowv[j][2]*rowv[j][2]+rowv[j][3]*rowv[j][3];
        #pragma unroll
        for (int o=1;o<16;o<<=1){ s += __shfl_xor(s,o); s2 += __shfl_xor(s2,o); }
        if (rl==0){
            int row = rblk*16 + g*4 + j;
            lnred[ch][row][0] = s;
            lnred[ch][row][1] = s2;
        }
    }
    __syncthreads();
    #pragma unroll
    for (int j=0;j<4;++j){
        int row = rblk*16 + g*4 + j;
        float S  = lnred[0][row][0] + lnred[1][row][0];
        float S2 = lnred[0][row][1] + lnred[1][row][1];
        float mean = S*(1.f/D);
        float var  = S2*(1.f/D) - mean*mean;
        float rs = rsqrtf(var + EPS);
        int m = bm*64 + row;
        #pragma unroll
        for (int dt=0;dt<4;++dt){
            int d = ch*64 + dt*16 + rl;
            float o1 = (rowv[j][dt]-mean)*rs*g1[d] + be1[d];
            x1b[(size_t)m*D + d] = f2b(o1);
            yacc[(size_t)m*D + d] = o1;
        }
    }
}

// ---------------- K4: gating ----------------
__global__ __launch_bounds__(128) void k_gate(
    const float* __restrict__ yacc, const float* __restrict__ Wg, const float* __restrict__ cls,
    float* __restrict__ gate, float* __restrict__ gate_out)
{
    __shared__ float xm[D];
    __shared__ float tt[D];
    __shared__ float se[E];
    int n = blockIdx.x, t = threadIdx.x;
    float s = 0.f;
    #pragma unroll
    for (int b=0;b<BS;++b) s += yacc[((size_t)b*NV + n)*D + t];
    xm[t] = s * (1.f/BS);
    __syncthreads();
    float a = 0.f;
    for (int c=0;c<D;++c) a += xm[c] * Wg[c*D + t];
    tt[t] = a;
    __syncthreads();
    if (t < E){
        float acc=0.f;
        for (int c=0;c<D;++c) acc += tt[c] * cls[t*D + c];
        se[t]=acc;
    }
    __syncthreads();
    if (t==0){
        float mx=se[0];
        for(int e=1;e<E;++e) mx=fmaxf(mx,se[e]);
        float sm=0.f; float p[E];
        for(int e=0;e<E;++e){ p[e]=__expf(se[e]-mx); sm+=p[e]; }
        float inv=1.f/sm;
        for(int e=0;e<E;++e){
            gate[n*E+e]     = p[e]*inv;
            gate_out[n*E+e] = p[e]*inv;
        }
    }
}

// ---------------- K6: fused MoE + residual + LN2 (32x32x16 MFMA) ----------------
__global__ __launch_bounds__(512) void k_moe_fused(
    const bf16* __restrict__ x1b, const bf16* __restrict__ W1b, const bf16* __restrict__ W2b,
    const float* __restrict__ b1eff, const float* __restrict__ b2,
    const float* __restrict__ gate, const float* __restrict__ yacc,
    const float* __restrict__ g2, const float* __restrict__ be2,
    float* __restrict__ out)
{
    __shared__ __align__(16) char smem[147456];
    char* Hl = smem + 131072;
    float (*lnred)[4][2] = (float (*)[4][2])Hl;

    int t = threadIdx.x;
    int w = t >> 6, lane = t & 63;
    int mb = w >> 2, nb = w & 3;
    int l31 = lane & 31, h = lane >> 5;
    int bm = blockIdx.x;

    sh8 afr[8];
    {
        const bf16* Ab = x1b + (size_t)(bm*64 + mb*32 + l31)*D;
        #pragma unroll
        for (int s=0;s<8;++s) afr[s] = *(const sh8*)(Ab + s*16 + h*8);
    }

    f32x16 oacc = {};
    f32x16 acc2e = {};

    auto STAGE = [&](int idx, int buf){
        int e = idx >> 2, fc = idx & 3;
        const bf16* w1src = W1b + ((size_t)e*DFF + fc*128)*(2*D);
        const bf16* w2src = W2b + (size_t)e*D*DFF + fc*128;
        char* Wa = smem + buf*65536;
        char* Wb = Wa + 32768;
        #pragma unroll
        for (int i=0;i<4;++i){
            int ci  = (i*8 + w)*64 + lane;
            int row = ci >> 4;
            int c16 = (ci & 15) ^ (row & 7);
            gload_lds16(w1src + (size_t)row*256 + c16*8, Wa + (size_t)(i*8+w)*1024);
            gload_lds16(w2src + (size_t)row*512 + c16*8, Wb + (size_t)(i*8+w)*1024);
        }
    };

    STAGE(0, 0);
    asm volatile("s_waitcnt vmcnt(0)" ::: "memory");
    __syncthreads();

    for (int idx=0; idx<32; ++idx){
        int buf = idx & 1;
        int e = idx >> 2, fc = idx & 3;
        char* Wa = smem + buf*65536;
        char* Wb = Wa + 32768;

        if (idx < 31) STAGE(idx+1, buf^1);

        f32x16 acc1 = {};
        {
            int row = nb*32 + l31;
            int rbase = (row<<8);
            int swz = (row&7)<<4;
            #pragma unroll
            for (int s=0;s<8;++s){
                int bo = (rbase + s*32 + h*16) ^ swz;
                sh8 bfr = *(const sh8*)(Wa + bo);
                acc1 = __builtin_amdgcn_mfma_f32_32x32x16_bf16(afr[s], bfr, acc1, 0,0,0);
            }
        }
        {
            float bia = b1eff[e*DFF + fc*128 + nb*32 + l31];
            #pragma unroll
            for (int r=0;r<16;++r){
                int rowm = mb*32 + (r&3) + 8*(r>>2) + 4*h;
                float v = acc1[r] + bia;
                v = v > 0.f ? v : 0.f;
                int bo = (rowm<<8) + ((nb*32 + l31)<<1);
                bo ^= (rowm&7)<<4;
                *(bf16*)(Hl + bo) = f2b(v);
            }
        }
        __syncthreads();

        {
            int rowh = mb*32 + l31;
            int hbase = (rowh<<8), hswz = (rowh&7)<<4;
            int roww = nb*32 + l31;
            int wbase = (roww<<8), wswz = (roww&7)<<4;
            #pragma unroll
            for (int s=0;s<8;++s){
                sh8 hfr = *(const sh8*)(Hl + ((hbase + s*32 + h*16) ^ hswz));
                sh8 wfr = *(const sh8*)(Wb + ((wbase + s*32 + h*16) ^ wswz));
                acc2e = __builtin_amdgcn_mfma_f32_32x32x16_bf16(hfr, wfr, acc2e, 0,0,0);
            }
        }

        if (fc == 3){
            int d = nb*32 + l31;
            float bia2 = b2[e*D + d];
            #pragma unroll
            for (int r=0;r<16;++r){
                int m = bm*64 + mb*32 + (r&3) + 8*(r>>2) + 4*h;
                float gv = gate[(m & 511)*E + e];
                oacc[r] += gv*(acc2e[r] + bia2);
            }
            acc2e = (f32x16){};
        }

        asm volatile("s_waitcnt vmcnt(0)" ::: "memory");
        __syncthreads();
    }

    int d = nb*32 + l31;
    float rowv[16];
    #pragma unroll
    for (int r=0;r<16;++r){
        int m = bm*64 + mb*32 + (r&3) + 8*(r>>2) + 4*h;
        rowv[r] = oacc[r] + yacc[(size_t)m*D + d];
    }
    #pragma unroll
    for (int r=0;r<16;++r){
        float s = rowv[r], s2 = rowv[r]*rowv[r];
        #pragma unroll
        for (int o=1;o<32;o<<=1){ s += __shfl_xor(s,o); s2 += __shfl_xor(s2,o); }
        if (l31==0){
            int rowl = mb*32 + (r&3) + 8*(r>>2) + 4*h;
            lnred[rowl][nb][0] = s;
            lnred[rowl][nb][1] = s2;
        }
    }
    __syncthreads();
    #pragma unroll
    for (int r=0;r<16;++r){
        int rowl = mb*32 + (r&3) + 8*(r>>2) + 4*h;
        float S  = lnred[rowl][0][0]+lnred[rowl][1][0]+lnred[rowl][2][0]+lnred[rowl][3][0];
        float S2 = lnred[rowl][0][1]+lnred[rowl][1][1]+lnred[rowl][2][1]+lnred[rowl][3][1];
        float mean = S*(1.f/D);
        float var  = S2*(1.f/D) - mean*mean;
        float rs = rsqrtf(var + EPS);
        int m = bm*64 + rowl;
        out[(size_t)m*D + d] = (rowv[r]-mean)*rs*g2[d] + be2[d];
    }
}

extern "C" void kernel_launch(void* const* d_in, const int* in_sizes, int n_in,
                              void* d_out, int out_size, void* d_ws, size_t ws_size,
                              hipStream_t stream)
{
    const float* x   = (const float*)d_in[0];
    const float* cls = (const float*)d_in[1];
    const float* Wq  = (const float*)d_in[2];
    const float* Wk  = (const float*)d_in[3];
    const float* Wv  = (const float*)d_in[4];
    const float* Wo  = (const float*)d_in[5];
    const float* Wg  = (const float*)d_in[6];
    const float* W1  = (const float*)d_in[7];
    const float* b1  = (const float*)d_in[8];
    const float* W2  = (const float*)d_in[9];
    const float* b2  = (const float*)d_in[10];
    const float* g1  = (const float*)d_in[11];
    const float* be1 = (const float*)d_in[12];
    const float* g2  = (const float*)d_in[13];
    const float* be2 = (const float*)d_in[14];

    float* out      = (float*)d_out;
    float* attn     = out + (size_t)M_TOK*D;
    float* gate_out = attn + (size_t)BS*NH*NV*NV;

    char* ws = (char*)d_ws;
    size_t off = 0;
    auto alloc = [&](size_t bytes)->void*{ void* p = ws + off; off += (bytes + 255) & ~(size_t)255; return p; };
    f16*   q    = (f16*)  alloc((size_t)M_TOK*D*2);
    f16*   kbuf = (f16*)  alloc((size_t)M_TOK*D*2);
    f16*   vbuf = (f16*)  alloc((size_t)M_TOK*D*2);
    f16*   ctx  = (f16*)  alloc((size_t)M_TOK*D*2);
    bf16*  x1b  = (bf16*) alloc((size_t)M_TOK*D*2);
    float* yacc = (float*)alloc((size_t)M_TOK*D*4);
    float* gate = (float*)alloc((size_t)NV*E*4);
    float* b1eff= (float*)alloc((size_t)E*DFF*4);
    bf16*  W1b  = (bf16*) alloc((size_t)E*DFF*2*D*2);
    bf16*  W2b  = (bf16*) alloc((size_t)E*D*DFF*2);
    f16*   xh   = (f16*)  alloc((size_t)M_TOK*D*2);
    f16*   WTq  = (f16*)  alloc((size_t)384*D*2);
    f16*   WoT  = (f16*)  alloc((size_t)D*D*2);

    k_prep<<<(PREP_ITEMS+255)/256, 256, 0, stream>>>(
        W1, W2, x, Wq, Wk, Wv, Wo, b1, cls,
        W1b, W2b, xh, WTq, WoT, b1eff);

    k_qkv_mfma<<<dim3(M_TOK/64, 2), 512, 0, stream>>>(xh, WTq, q, kbuf, vbuf);
    k_attn2<<<dim3(BS*NH, NV/64), 256, 0, stream>>>(q, kbuf, vbuf, attn, ctx);
    k_woln_mfma<<<M_TOK/64, 512, 0, stream>>>(ctx, WoT, x, g1, be1, x1b, yacc);
    k_gate<<<NV, 128, 0, stream>>>(yacc, Wg, cls, gate, gate_out);
    k_moe_fused<<<256, 512, 0, stream>>>(x1b, W1b, W2b, b1eff, b2, gate, yacc, g2, be2, out);
}

// Round 15
// 164.106 us; speedup vs baseline: 1.9546x; 1.1225x over previous
//
#include <hip/hip_runtime.h>
#include <hip/hip_bf16.h>
#include <math.h>

#define BS   32
#define NV   512
#define D    128
#define DFF  512
#define E    8
#define NH   8
#define DH   16
#define M_TOK (BS*NV)      // 16384
#define EPS  1e-5f

typedef __hip_bfloat16 bf16;
typedef _Float16 f16;
using sh8   = __attribute__((ext_vector_type(8))) short;    // 8 bf16 (4 VGPRs)
using us4   = __attribute__((ext_vector_type(4))) unsigned short;
using h4    = __attribute__((ext_vector_type(4))) _Float16;
using h8    = __attribute__((ext_vector_type(8))) _Float16; // 8 f16 (4 VGPRs)
using f32x4 = __attribute__((ext_vector_type(4))) float;
using f32x16 = __attribute__((ext_vector_type(16))) float;

__device__ __forceinline__ float b2f(bf16 v){ return __bfloat162float(v); }
__device__ __forceinline__ bf16  f2b(float v){ return __float2bfloat16(v); }
__device__ __forceinline__ unsigned short f2bu(float v){
    bf16 b = __float2bfloat16(v);
    return __builtin_bit_cast(unsigned short, b);
}

// async global->LDS, 16B per lane; LDS dest is wave-uniform base + lane*16
__device__ __forceinline__ void gload_lds16(const void* g, void* l){
    __builtin_amdgcn_global_load_lds(
        (const __attribute__((address_space(1))) unsigned int*)g,
        (__attribute__((address_space(3))) unsigned int*)l, 16, 0, 0);
}

// ---------------- K0: consolidated prep (all conversions + b1eff) ----------------
#define PR0 4096                    // b1eff
#define PR1 (PR0 + 262144)          // W1b  (vec4)
#define PR2 (PR1 + 131072)          // W2b  (vec4)
#define PR3 (PR2 + 524288)          // xh   (vec4)
#define PR4 (PR3 + 49152)           // WTq transpose
#define PR5 (PR4 + 16384)           // WoT transpose
#define PREP_ITEMS PR5              // 987,136
__global__ __launch_bounds__(256) void k_prep(
    const float* __restrict__ W1, const float* __restrict__ W2,
    const float* __restrict__ x,  const float* __restrict__ Wq,
    const float* __restrict__ Wk, const float* __restrict__ Wv,
    const float* __restrict__ Wo, const float* __restrict__ b1,
    const float* __restrict__ cls,
    bf16* __restrict__ W1b, bf16* __restrict__ W2b, f16* __restrict__ xh,
    f16* __restrict__ WTq, f16* __restrict__ WoT, float* __restrict__ b1eff)
{
    int tid = blockIdx.x*256 + threadIdx.x;
    if (tid < PR0){
        int e = tid >> 9, f = tid & 511;
        float acc = b1[e*DFF + f];
        const float* wrow = W1 + ((size_t)e*DFF + f)*(2*D) + D;
        #pragma unroll 8
        for (int c=0;c<D;++c) acc += cls[e*D+c] * wrow[c];
        b1eff[tid] = acc;
    } else if (tid < PR1){
        int i = (tid - PR0)*4;
        float4 vv = *(const float4*)(W1 + i);
        us4 o; o[0]=f2bu(vv.x); o[1]=f2bu(vv.y); o[2]=f2bu(vv.z); o[3]=f2bu(vv.w);
        *(us4*)(W1b + i) = o;
    } else if (tid < PR2){
        int i = (tid - PR1)*4;
        float4 vv = *(const float4*)(W2 + i);
        us4 o; o[0]=f2bu(vv.x); o[1]=f2bu(vv.y); o[2]=f2bu(vv.z); o[3]=f2bu(vv.w);
        *(us4*)(W2b + i) = o;
    } else if (tid < PR3){
        int i = (tid - PR2)*4;
        float4 vv = *(const float4*)(x + i);
        h4 o; o[0]=(f16)vv.x; o[1]=(f16)vv.y; o[2]=(f16)vv.z; o[3]=(f16)vv.w;
        *(h4*)(xh + i) = o;
    } else if (tid < PR4){
        int idx = tid - PR3;
        int c = idx>>7, kk = idx&127;
        int which = c>>7, col = c&127;
        const float* W = which==0?Wq:(which==1?Wk:Wv);
        WTq[idx] = (f16)W[kk*D + col];
    } else if (tid < PR5){
        int idx = tid - PR4;
        int c = idx>>7, kk = idx&127;
        WoT[idx] = (f16)Wo[kk*D + c];
    }
}

// ---------------- K1: QKV projection (MFMA f16 GEMM) ----------------
__global__ __launch_bounds__(512) void k_qkv_mfma(
    const f16* __restrict__ xh, const f16* __restrict__ WT,
    f16* __restrict__ q, f16* __restrict__ k, f16* __restrict__ v)
{
    __shared__ __align__(16) char smem[65536];  // Xl 16K | Wl 48K
    char* Xl = smem;
    char* Wl = smem + 16384;
    int t = threadIdx.x;
    int w = t>>6, lane = t&63;
    int bm = blockIdx.x, nh = blockIdx.y;

    const f16* xsrc = xh + (size_t)bm*64*D;
    #pragma unroll
    for (int i=0;i<2;++i){
        int ci = i*512 + t;
        int row = ci>>4, c16 = (ci&15)^(row&7);
        gload_lds16(xsrc + row*D + c16*8, Xl + (size_t)(i*512 + w*64)*16);
    }
    const f16* wsrc = WT + (size_t)nh*192*D;
    #pragma unroll
    for (int i=0;i<6;++i){
        int ci = i*512 + t;
        int row = ci>>4, c16 = (ci&15)^(row&7);
        gload_lds16(wsrc + row*D + c16*8, Wl + (size_t)(i*512 + w*64)*16);
    }
    __syncthreads();

    int rblk = w>>1, ch = w&1;
    int rl = lane&15, g = lane>>4;

    h8 afr[4];
    #pragma unroll
    for (int kk=0;kk<4;++kk){
        int row = rblk*16 + rl;
        int bo = (row<<8) + (kk<<6) + (g<<4); bo ^= (row&7)<<4;
        afr[kk] = *(const h8*)(Xl + bo);
    }
    f32x4 acc[6];
    #pragma unroll
    for (int nt=0;nt<6;++nt) acc[nt] = (f32x4){0.f,0.f,0.f,0.f};
    #pragma unroll
    for (int nt=0; nt<6; ++nt){
        #pragma unroll
        for (int kk=0;kk<4;++kk){
            int row = ch*96 + nt*16 + rl;
            int bo = (row<<8)+(kk<<6)+(g<<4); bo ^= (row&7)<<4;
            h8 bfr = *(const h8*)(Wl + bo);
            acc[nt] = __builtin_amdgcn_mfma_f32_16x16x32_f16(afr[kk], bfr, acc[nt],0,0,0);
        }
    }
    #pragma unroll
    for (int nt=0;nt<6;++nt){
        int cidx = nh*192 + ch*96 + nt*16 + rl;
        int which = cidx>>7, hh=(cidx>>4)&7, d = cidx&15;
        f16* dst = which==0?q:(which==1?k:v);
        #pragma unroll
        for (int j=0;j<4;++j){
            int m = bm*64 + rblk*16 + g*4 + j;
            int b = m>>9, n = m&511;
            dst[(((size_t)(b*NH+hh))*NV + n)*DH + d] = (f16)acc[nt][j];
        }
    }
}

// ---------------- K2: MFMA attention (r12 form + early q prefetch) ----------------
#define KSTRIDE 24
#define VSTRIDE 520
#define PSTRIDE 68
__global__ __launch_bounds__(256) void k_attn2(
    const f16* __restrict__ q, const f16* __restrict__ kin, const f16* __restrict__ vin,
    float* __restrict__ attn_out, f16* __restrict__ ctx)
{
    __shared__ f16  Kl[512*KSTRIDE];       // 24 KB
    __shared__ f16  VT[16*VSTRIDE];        // 16.25 KB
    __shared__ f16  pbh[4][16*PSTRIDE];    // 8.5 KB, per-wave P chunk [q][kv+pad]

    int bh = blockIdx.x;
    int t  = threadIdx.x;
    int wave = t >> 6, lane = t & 63;
    int ql = lane & 15, g = lane >> 4;
    int q0 = blockIdx.y*64 + wave*16;

    // issue q load early: latency hides under K/V staging (T14 issue-early)
    h4 qf = *(const h4*)(q + ((size_t)bh*NV + q0 + ql)*DH + 4*g);

    const f16* kb = kin + (size_t)bh*NV*DH;
    const f16* vb = vin + (size_t)bh*NV*DH;
    {
        int r0 = t*2;
        #pragma unroll
        for (int rr=0; rr<2; ++rr){
            const uint4* src = (const uint4*)(kb + (size_t)(r0+rr)*DH);
            *((uint4*)(Kl + (r0+rr)*KSTRIDE))     = src[0];
            *((uint4*)(Kl + (r0+rr)*KSTRIDE + 8)) = src[1];
        }
        const unsigned short* v0s = (const unsigned short*)(vb + (size_t)r0*DH);
        const unsigned short* v1s = v0s + DH;
        #pragma unroll
        for (int d=0; d<DH; ++d){
            unsigned u = (unsigned)v0s[d] | ((unsigned)v1s[d] << 16);
            *((unsigned*)(VT + d*VSTRIDE + r0)) = u;
        }
    }
    __syncthreads();

    #pragma unroll
    for (int i=0;i<4;++i) qf[i] = qf[i] * (_Float16)0.36067376f; // 0.25*log2(e)

    f32x4 S[32];
    #pragma unroll
    for (int tt=0; tt<32; ++tt){
        h4 kf = *(const h4*)(Kl + (tt*16 + ql)*KSTRIDE + 4*g);
        S[tt] = __builtin_amdgcn_mfma_f32_16x16x16f16(kf, qf, (f32x4){0.f,0.f,0.f,0.f}, 0,0,0);
    }

    // softmax (no max-subtract: scores tiny; exp2 base folded into q-scale)
    float sum = 0.f;
    #pragma unroll
    for (int tt=0; tt<32; ++tt)
        #pragma unroll
        for (int j=0;j<4;++j){
            float p = exp2f(S[tt][j]);
            S[tt][j] = p; sum += p;
        }
    sum += __shfl_xor(sum, 16);
    sum += __shfl_xor(sum, 32);
    float inv = 1.f/sum;
    #pragma unroll
    for (int tt=0; tt<32; ++tt)
        #pragma unroll
        for (int j=0;j<4;++j) S[tt][j] *= inv;

    f32x4 o0 = (f32x4){0.f,0.f,0.f,0.f}, o1 = (f32x4){0.f,0.f,0.f,0.f};
    f16* pw = pbh[wave];
    float* attnbase = attn_out + ((size_t)bh*NV + q0)*NV;
    int col16 = lane & 15, qg = lane >> 4;
    #pragma unroll
    for (int c=0; c<8; ++c){
        #pragma unroll
        for (int tt2=0; tt2<4; ++tt2){
            int tt = c*4 + tt2;
            h4 pf;
            pf[0]=(f16)S[tt][0]; pf[1]=(f16)S[tt][1];
            pf[2]=(f16)S[tt][2]; pf[3]=(f16)S[tt][3];
            h4 vf = *(const h4*)(VT + ql*VSTRIDE + tt*16 + 4*g);
            if (tt&1) o1 = __builtin_amdgcn_mfma_f32_16x16x16f16(vf, pf, o1, 0,0,0);
            else      o0 = __builtin_amdgcn_mfma_f32_16x16x16f16(vf, pf, o0, 0,0,0);
            *(h4*)(pw + ql*PSTRIDE + tt2*16 + 4*g) = pf;   // one b64 write
        }
        asm volatile("" ::: "memory");   // compiler fence; HW keeps per-wave DS order
        #pragma unroll
        for (int rr=0; rr<4; ++rr){
            int qq = rr*4 + qg;
            h4 hv = *(const h4*)(pw + qq*PSTRIDE + col16*4);   // one b64 read
            f32x4 vv;
            vv[0]=(float)hv[0]; vv[1]=(float)hv[1];
            vv[2]=(float)hv[2]; vv[3]=(float)hv[3];
            // per instruction: 4 rows x (16 lanes x 16B = 256 B contiguous)
            __builtin_nontemporal_store(vv, (f32x4*)(attnbase + (size_t)qq*NV + c*64 + col16*4));
        }
        asm volatile("" ::: "memory");   // fence before next chunk's pw writes (WAR)
    }
    f32x4 o = o0 + o1;
    int b = bh >> 3, h = bh & 7;
    f16* cb = ctx + ((size_t)(b*NV) + q0 + ql)*D + h*DH + 4*g;
    h4 oc; oc[0]=(f16)o[0]; oc[1]=(f16)o[1]; oc[2]=(f16)o[2]; oc[3]=(f16)o[3];
    *(h4*)cb = oc;
}

// ---------------- K3: Wo projection + residual + LN1 (MFMA) ----------------
__global__ __launch_bounds__(512) void k_woln_mfma(
    const f16* __restrict__ ctx, const f16* __restrict__ WoT,
    const float* __restrict__ x, const float* __restrict__ g1, const float* __restrict__ be1,
    bf16* __restrict__ x1b, float* __restrict__ yacc)
{
    __shared__ __align__(16) char smem[49152];  // Cl 16K | Wl 32K
    __shared__ float lnred[2][64][2];
    char* Cl = smem;
    char* Wl = smem + 16384;
    int t = threadIdx.x;
    int w = t>>6, lane = t&63;
    int bm = blockIdx.x;

    const f16* csrc = ctx + (size_t)bm*64*D;
    #pragma unroll
    for (int i=0;i<2;++i){
        int ci = i*512 + t;
        int row = ci>>4, c16 = (ci&15)^(row&7);
        gload_lds16(csrc + row*D + c16*8, Cl + (size_t)(i*512 + w*64)*16);
    }
    #pragma unroll
    for (int i=0;i<4;++i){
        int ci = i*512 + t;
        int row = ci>>4, c16 = (ci&15)^(row&7);
        gload_lds16(WoT + row*D + c16*8, Wl + (size_t)(i*512 + w*64)*16);
    }
    __syncthreads();

    int rblk = w>>1, ch = w&1;
    int rl = lane&15, g = lane>>4;

    h8 afr[4];
    #pragma unroll
    for (int kk=0;kk<4;++kk){
        int row = rblk*16 + rl;
        int bo = (row<<8) + (kk<<6) + (g<<4); bo ^= (row&7)<<4;
        afr[kk] = *(const h8*)(Cl + bo);
    }
    f32x4 acc[4];
    #pragma unroll
    for (int nt=0;nt<4;++nt) acc[nt] = (f32x4){0.f,0.f,0.f,0.f};
    #pragma unroll
    for (int nt=0; nt<4; ++nt){
        #pragma unroll
        for (int kk=0;kk<4;++kk){
            int row = ch*64 + nt*16 + rl;
            int bo = (row<<8)+(kk<<6)+(g<<4); bo ^= (row&7)<<4;
            h8 bfr = *(const h8*)(Wl + bo);
            acc[nt] = __builtin_amdgcn_mfma_f32_16x16x32_f16(afr[kk], bfr, acc[nt],0,0,0);
        }
    }

    float rowv[4][4];
    #pragma unroll
    for (int j=0;j<4;++j){
        int m = bm*64 + rblk*16 + g*4 + j;
        #pragma unroll
        for (int dt=0;dt<4;++dt){
            int d = ch*64 + dt*16 + rl;
            rowv[j][dt] = acc[dt][j] + x[(size_t)m*D + d];
        }
    }
    #pragma unroll
    for (int j=0;j<4;++j){
        float s  = rowv[j][0]+rowv[j][1]+rowv[j][2]+rowv[j][3];
        float s2 = rowv[j][0]*rowv[j][0]+rowv[j][1]*rowv[j][1]
                 + rowv[j][2]*rowv[j][2]+rowv[j][3]*rowv[j][3];
        #pragma unroll
        for (int o=1;o<16;o<<=1){ s += __shfl_xor(s,o); s2 += __shfl_xor(s2,o); }
        if (rl==0){
            int row = rblk*16 + g*4 + j;
            lnred[ch][row][0] = s;
            lnred[ch][row][1] = s2;
        }
    }
    __syncthreads();
    #pragma unroll
    for (int j=0;j<4;++j){
        int row = rblk*16 + g*4 + j;
        float S  = lnred[0][row][0] + lnred[1][row][0];
        float S2 = lnred[0][row][1] + lnred[1][row][1];
        float mean = S*(1.f/D);
        float var  = S2*(1.f/D) - mean*mean;
        float rs = rsqrtf(var + EPS);
        int m = bm*64 + row;
        #pragma unroll
        for (int dt=0;dt<4;++dt){
            int d = ch*64 + dt*16 + rl;
            float o1 = (rowv[j][dt]-mean)*rs*g1[d] + be1[d];
            x1b[(size_t)m*D + d] = f2b(o1);
            yacc[(size_t)m*D + d] = o1;
        }
    }
}

// ---------------- K4: gating ----------------
__global__ __launch_bounds__(128) void k_gate(
    const float* __restrict__ yacc, const float* __restrict__ Wg, const float* __restrict__ cls,
    float* __restrict__ gate, float* __restrict__ gate_out)
{
    __shared__ float xm[D];
    __shared__ float tt[D];
    __shared__ float se[E];
    int n = blockIdx.x, t = threadIdx.x;
    float s = 0.f;
    #pragma unroll
    for (int b=0;b<BS;++b) s += yacc[((size_t)b*NV + n)*D + t];
    xm[t] = s * (1.f/BS);
    __syncthreads();
    float a = 0.f;
    for (int c=0;c<D;++c) a += xm[c] * Wg[c*D + t];
    tt[t] = a;
    __syncthreads();
    if (t < E){
        float acc=0.f;
        for (int c=0;c<D;++c) acc += tt[c] * cls[t*D + c];
        se[t]=acc;
    }
    __syncthreads();
    if (t==0){
        float mx=se[0];
        for(int e=1;e<E;++e) mx=fmaxf(mx,se[e]);
        float sm=0.f; float p[E];
        for(int e=0;e<E;++e){ p[e]=__expf(se[e]-mx); sm+=p[e]; }
        float inv=1.f/sm;
        for(int e=0;e<E;++e){
            gate[n*E+e]     = p[e]*inv;
            gate_out[n*E+e] = p[e]*inv;
        }
    }
}

// ---------------- K6: fused MoE + residual + LN2 (32x32x16 MFMA) ----------------
__global__ __launch_bounds__(512) void k_moe_fused(
    const bf16* __restrict__ x1b, const bf16* __restrict__ W1b, const bf16* __restrict__ W2b,
    const float* __restrict__ b1eff, const float* __restrict__ b2,
    const float* __restrict__ gate, const float* __restrict__ yacc,
    const float* __restrict__ g2, const float* __restrict__ be2,
    float* __restrict__ out)
{
    __shared__ __align__(16) char smem[147456];
    char* Hl = smem + 131072;
    float (*lnred)[4][2] = (float (*)[4][2])Hl;

    int t = threadIdx.x;
    int w = t >> 6, lane = t & 63;
    int mb = w >> 2, nb = w & 3;
    int l31 = lane & 31, h = lane >> 5;
    int bm = blockIdx.x;

    sh8 afr[8];
    {
        const bf16* Ab = x1b + (size_t)(bm*64 + mb*32 + l31)*D;
        #pragma unroll
        for (int s=0;s<8;++s) afr[s] = *(const sh8*)(Ab + s*16 + h*8);
    }

    f32x16 oacc = {};
    f32x16 acc2e = {};

    auto STAGE = [&](int idx, int buf){
        int e = idx >> 2, fc = idx & 3;
        const bf16* w1src = W1b + ((size_t)e*DFF + fc*128)*(2*D);
        const bf16* w2src = W2b + (size_t)e*D*DFF + fc*128;
        char* Wa = smem + buf*65536;
        char* Wb = Wa + 32768;
        #pragma unroll
        for (int i=0;i<4;++i){
            int ci  = (i*8 + w)*64 + lane;
            int row = ci >> 4;
            int c16 = (ci & 15) ^ (row & 7);
            gload_lds16(w1src + (size_t)row*256 + c16*8, Wa + (size_t)(i*8+w)*1024);
            gload_lds16(w2src + (size_t)row*512 + c16*8, Wb + (size_t)(i*8+w)*1024);
        }
    };

    STAGE(0, 0);
    asm volatile("s_waitcnt vmcnt(0)" ::: "memory");
    __syncthreads();

    for (int idx=0; idx<32; ++idx){
        int buf = idx & 1;
        int e = idx >> 2, fc = idx & 3;
        char* Wa = smem + buf*65536;
        char* Wb = Wa + 32768;

        if (idx < 31) STAGE(idx+1, buf^1);

        f32x16 acc1 = {};
        {
            int row = nb*32 + l31;
            int rbase = (row<<8);
            int swz = (row&7)<<4;
            #pragma unroll
            for (int s=0;s<8;++s){
                int bo = (rbase + s*32 + h*16) ^ swz;
                sh8 bfr = *(const sh8*)(Wa + bo);
                acc1 = __builtin_amdgcn_mfma_f32_32x32x16_bf16(afr[s], bfr, acc1, 0,0,0);
            }
        }
        {
            float bia = b1eff[e*DFF + fc*128 + nb*32 + l31];
            #pragma unroll
            for (int r=0;r<16;++r){
                int rowm = mb*32 + (r&3) + 8*(r>>2) + 4*h;
                float v = acc1[r] + bia;
                v = v > 0.f ? v : 0.f;
                int bo = (rowm<<8) + ((nb*32 + l31)<<1);
                bo ^= (rowm&7)<<4;
                *(bf16*)(Hl + bo) = f2b(v);
            }
        }
        __syncthreads();

        {
            int rowh = mb*32 + l31;
            int hbase = (rowh<<8), hswz = (rowh&7)<<4;
            int roww = nb*32 + l31;
            int wbase = (roww<<8), wswz = (roww&7)<<4;
            #pragma unroll
            for (int s=0;s<8;++s){
                sh8 hfr = *(const sh8*)(Hl + ((hbase + s*32 + h*16) ^ hswz));
                sh8 wfr = *(const sh8*)(Wb + ((wbase + s*32 + h*16) ^ wswz));
                acc2e = __builtin_amdgcn_mfma_f32_32x32x16_bf16(hfr, wfr, acc2e, 0,0,0);
            }
        }

        if (fc == 3){
            int d = nb*32 + l31;
            float bia2 = b2[e*D + d];
            #pragma unroll
            for (int r=0;r<16;++r){
                int m = bm*64 + mb*32 + (r&3) + 8*(r>>2) + 4*h;
                float gv = gate[(m & 511)*E + e];
                oacc[r] += gv*(acc2e[r] + bia2);
            }
            acc2e = (f32x16){};
        }

        asm volatile("s_waitcnt vmcnt(0)" ::: "memory");
        __syncthreads();
    }

    int d = nb*32 + l31;
    float rowv[16];
    #pragma unroll
    for (int r=0;r<16;++r){
        int m = bm*64 + mb*32 + (r&3) + 8*(r>>2) + 4*h;
        rowv[r] = oacc[r] + yacc[(size_t)m*D + d];
    }
    #pragma unroll
    for (int r=0;r<16;++r){
        float s = rowv[r], s2 = rowv[r]*rowv[r];
        #pragma unroll
        for (int o=1;o<32;o<<=1){ s += __shfl_xor(s,o); s2 += __shfl_xor(s2,o); }
        if (l31==0){
            int rowl = mb*32 + (r&3) + 8*(r>>2) + 4*h;
            lnred[rowl][nb][0] = s;
            lnred[rowl][nb][1] = s2;
        }
    }
    __syncthreads();
    #pragma unroll
    for (int r=0;r<16;++r){
        int rowl = mb*32 + (r&3) + 8*(r>>2) + 4*h;
        float S  = lnred[rowl][0][0]+lnred[rowl][1][0]+lnred[rowl][2][0]+lnred[rowl][3][0];
        float S2 = lnred[rowl][0][1]+lnred[rowl][1][1]+lnred[rowl][2][1]+lnred[rowl][3][1];
        float mean = S*(1.f/D);
        float var  = S2*(1.f/D) - mean*mean;
        float rs = rsqrtf(var + EPS);
        int m = bm*64 + rowl;
        out[(size_t)m*D + d] = (rowv[r]-mean)*rs*g2[d] + be2[d];
    }
}

extern "C" void kernel_launch(void* const* d_in, const int* in_sizes, int n_in,
                              void* d_out, int out_size, void* d_ws, size_t ws_size,
                              hipStream_t stream)
{
    const float* x   = (const float*)d_in[0];
    const float* cls = (const float*)d_in[1];
    const float* Wq  = (const float*)d_in[2];
    const float* Wk  = (const float*)d_in[3];
    const float* Wv  = (const float*)d_in[4];
    const float* Wo  = (const float*)d_in[5];
    const float* Wg  = (const float*)d_in[6];
    const float* W1  = (const float*)d_in[7];
    const float* b1  = (const float*)d_in[8];
    const float* W2  = (const float*)d_in[9];
    const float* b2  = (const float*)d_in[10];
    const float* g1  = (const float*)d_in[11];
    const float* be1 = (const float*)d_in[12];
    const float* g2  = (const float*)d_in[13];
    const float* be2 = (const float*)d_in[14];

    float* out      = (float*)d_out;
    float* attn     = out + (size_t)M_TOK*D;
    float* gate_out = attn + (size_t)BS*NH*NV*NV;

    char* ws = (char*)d_ws;
    size_t off = 0;
    auto alloc = [&](size_t bytes)->void*{ void* p = ws + off; off += (bytes + 255) & ~(size_t)255; return p; };
    f16*   q    = (f16*)  alloc((size_t)M_TOK*D*2);
    f16*   kbuf = (f16*)  alloc((size_t)M_TOK*D*2);
    f16*   vbuf = (f16*)  alloc((size_t)M_TOK*D*2);
    f16*   ctx  = (f16*)  alloc((size_t)M_TOK*D*2);
    bf16*  x1b  = (bf16*) alloc((size_t)M_TOK*D*2);
    float* yacc = (float*)alloc((size_t)M_TOK*D*4);
    float* gate = (float*)alloc((size_t)NV*E*4);
    float* b1eff= (float*)alloc((size_t)E*DFF*4);
    bf16*  W1b  = (bf16*) alloc((size_t)E*DFF*2*D*2);
    bf16*  W2b  = (bf16*) alloc((size_t)E*D*DFF*2);
    f16*   xh   = (f16*)  alloc((size_t)M_TOK*D*2);
    f16*   WTq  = (f16*)  alloc((size_t)384*D*2);
    f16*   WoT  = (f16*)  alloc((size_t)D*D*2);

    k_prep<<<(PREP_ITEMS+255)/256, 256, 0, stream>>>(
        W1, W2, x, Wq, Wk, Wv, Wo, b1, cls,
        W1b, W2b, xh, WTq, WoT, b1eff);

    k_qkv_mfma<<<dim3(M_TOK/64, 2), 512, 0, stream>>>(xh, WTq, q, kbuf, vbuf);
    k_attn2<<<dim3(BS*NH, NV/64), 256, 0, stream>>>(q, kbuf, vbuf, attn, ctx);
    k_woln_mfma<<<M_TOK/64, 512, 0, stream>>>(ctx, WoT, x, g1, be1, x1b, yacc);
    k_gate<<<NV, 128, 0, stream>>>(yacc, Wg, cls, gate, gate_out);
    k_moe_fused<<<256, 512, 0, stream>>>(x1b, W1b, W2b, b1eff, b2, gate, yacc, g2, be2, out);
}